// Round 7
// baseline (343.320 us; speedup 1.0000x reference)
//
#include <hip/hip_runtime.h>
#include <hip/hip_bf16.h>
#include <hip/hip_fp16.h>

#define B_  128
#define S_  512
#define H_  64
#define E_  64
#define G3  192   // 3*H
#define V_  4996
#define VCHUNK 32

typedef float f32x2 __attribute__((ext_vector_type(2)));
typedef float f32x4 __attribute__((ext_vector_type(4)));
typedef unsigned int u32;
typedef u32 u32x4 __attribute__((ext_vector_type(4)));
typedef _Float16 f16;
typedef f16 f16x2 __attribute__((ext_vector_type(2)));

__device__ __forceinline__ float sigmoidf_(float x) {
    return 1.0f / (1.0f + __expf(-x));
}

__device__ __forceinline__ float tanh_fast(float x) {
    x = fminf(fmaxf(x, -15.0f), 15.0f);
    const float e = __expf(2.0f * x);
    return (e - 1.0f) / (e + 1.0f);
}

// D = a.x*b.x + a.y*b.y + c  (v_dot2_f32_f16), fallback if builtin missing
__device__ __forceinline__ float fdot2_(u32 a, u32 b, float c) {
#if __has_builtin(__builtin_amdgcn_fdot2)
    return __builtin_amdgcn_fdot2(__builtin_bit_cast(f16x2, a),
                                  __builtin_bit_cast(f16x2, b), c, false);
#else
    const f16x2 av = __builtin_bit_cast(f16x2, a);
    const f16x2 bv = __builtin_bit_cast(f16x2, b);
    return fmaf((float)av.x, (float)bv.x, fmaf((float)av.y, (float)bv.y, c));
#endif
}

// ---------------------------------------------------------------------------
// Kernel 1: pre-project the embedding table through the input kernels (fp32).
//   proj[dir][v][j] = sum_e emb[v][e] * W_dir[e][j] + bi_dir[j]
// ---------------------------------------------------------------------------
__global__ __launch_bounds__(192) void proj_kernel(
    const float* __restrict__ emb,
    const float* __restrict__ Wf, const float* __restrict__ bif,
    const float* __restrict__ Wb, const float* __restrict__ bib,
    float* __restrict__ proj)            // [2][V][192]
{
    const int dir = blockIdx.y;
    const float* W  = dir ? Wb  : Wf;
    const float* bi = dir ? bib : bif;
    const int v0 = blockIdx.x * VCHUNK;
    const int j  = threadIdx.x;
    const int nrows = min(VCHUNK, V_ - v0);

    __shared__ __align__(16) float s_e[VCHUNK * E_];
    for (int i = j; i < nrows * E_; i += 192) s_e[i] = emb[(size_t)v0 * E_ + i];

    float wcol[E_];
    #pragma unroll
    for (int e = 0; e < E_; ++e) wcol[e] = W[e * G3 + j];
    const float bij = bi[j];
    __syncthreads();

    for (int r = 0; r < nrows; ++r) {
        const float4* x4 = (const float4*)(s_e + r * E_);
        float a0 = 0.f, a1 = 0.f, a2 = 0.f, a3 = 0.f;
        #pragma unroll
        for (int e4 = 0; e4 < 16; e4 += 4) {
            float4 h0 = x4[e4], h1 = x4[e4+1], h2 = x4[e4+2], h3 = x4[e4+3];
            a0 = fmaf(h0.x, wcol[4*e4+ 0], a0); a0 = fmaf(h0.y, wcol[4*e4+ 1], a0);
            a0 = fmaf(h0.z, wcol[4*e4+ 2], a0); a0 = fmaf(h0.w, wcol[4*e4+ 3], a0);
            a1 = fmaf(h1.x, wcol[4*e4+ 4], a1); a1 = fmaf(h1.y, wcol[4*e4+ 5], a1);
            a1 = fmaf(h1.z, wcol[4*e4+ 6], a1); a1 = fmaf(h1.w, wcol[4*e4+ 7], a1);
            a2 = fmaf(h2.x, wcol[4*e4+ 8], a2); a2 = fmaf(h2.y, wcol[4*e4+ 9], a2);
            a2 = fmaf(h2.z, wcol[4*e4+10], a2); a2 = fmaf(h2.w, wcol[4*e4+11], a2);
            a3 = fmaf(h3.x, wcol[4*e4+12], a3); a3 = fmaf(h3.y, wcol[4*e4+13], a3);
            a3 = fmaf(h3.z, wcol[4*e4+14], a3); a3 = fmaf(h3.w, wcol[4*e4+15], a3);
        }
        proj[((size_t)dir * V_ + v0 + r) * G3 + j] = ((a0 + a1) + (a2 + a3)) + bij;
    }
}

// Kernel 2: pack recurrent kernels to f16 pairs, column-major per gate column:
//   Uh[dir][j][kk] = pack_f16(U[2kk][j], U[2kk+1][j])   kk in [0,32)
__global__ void upack_kernel(const float* __restrict__ Uf,
                             const float* __restrict__ Ub,
                             u32* __restrict__ Uh)    // [2][192][32]
{
    const int dir = blockIdx.x;
    const float* U = dir ? Ub : Uf;
    u32* o = Uh + (size_t)dir * G3 * 32;
    for (int k = threadIdx.x; k < G3 * 32; k += blockDim.x) {
        const int j = k >> 5, kk = k & 31;
        f16x2 p;
        p.x = (f16)U[(2 * kk    ) * G3 + j];
        p.y = (f16)U[(2 * kk + 1) * G3 + j];
        o[(size_t)j * 32 + kk] = __builtin_bit_cast(u32, p);
    }
}

// ---------------------------------------------------------------------------
// Kernel 3: the sequential scan. ONE WAVE per (batch row, direction).
// Lane u owns unit u; all three gate columns (u, u+64, u+128) computed
// in-lane via v_dot2_f32_f16 against f16-packed U columns held in 96 pinned
// VGPRs (fits the register file -> no spill, no per-step L2 weight refetch,
// which was the R3/R5/R6 bottleneck). h lives in one 128-B f16 LDS row
// (8 broadcast ds_read_b128/step); outputs go straight to global (coalesced,
// never waited on). No barriers, no shuffles.
// ---------------------------------------------------------------------------
__global__ __launch_bounds__(64)
__attribute__((amdgpu_waves_per_eu(1, 1)))
void gru_scan6(
    const int*   __restrict__ inputs,   // [B,S]
    const float* __restrict__ proj,     // [2][V][192]
    const u32*   __restrict__ Uh,       // [2][192][32] f16-pairs
    const float* __restrict__ brf, const float* __restrict__ brb,
    float* __restrict__ gru_out)        // [B,S,2H]
{
    const int b   = blockIdx.x >> 1;
    const int dir = blockIdx.x & 1;
    const int u   = threadIdx.x;           // == unit

    const float* eproj = proj + (size_t)dir * V_ * G3;
    const float* br    = dir ? brb : brf;

    __shared__ int s_idx[S_];
    __shared__ __align__(16) f16 s_h[H_];  // single row; same-wave DS is in-order

    for (int t = u; t < S_; t += 64) s_idx[t] = inputs[b * S_ + t];
    s_h[u] = (f16)0.0f;
    __builtin_amdgcn_wave_barrier();       // compiler ordering only, no HW cost

    // f16-packed U columns: 3 x 8 x u32x4 = 96 VGPRs, pinned (asm-defined =>
    // non-rematerializable; small enough to never spill).
    u32x4 wz[8], wr[8], wc[8];
    {
        const u32x4* pz = (const u32x4*)(Uh + ((size_t)dir * G3 + u      ) * 32);
        const u32x4* pr = (const u32x4*)(Uh + ((size_t)dir * G3 + u + 64 ) * 32);
        const u32x4* pc = (const u32x4*)(Uh + ((size_t)dir * G3 + u + 128) * 32);
        #pragma unroll
        for (int k = 0; k < 8; ++k) { wz[k] = pz[k]; wr[k] = pr[k]; wc[k] = pc[k]; }
        #pragma unroll
        for (int k = 0; k < 8; ++k) {
            asm volatile("" : "+v"(wz[k]));
            asm volatile("" : "+v"(wr[k]));
            asm volatile("" : "+v"(wc[k]));
        }
    }
    const float br0 = br[u], br1 = br[u + 64], br2 = br[u + 128];
    float hprev = 0.0f;

    // 4-step-ahead xw prefetch straight into registers (unrolled rotation)
    float xw0[4], xw1[4], xw2[4];
    int   tokp[4];
    auto pref = [&](int tstep, int p) {
        if (tstep < S_) {
            const int tt = dir ? (S_ - 1 - tstep) : tstep;
            int tk = s_idx[tt];
            tk = __builtin_amdgcn_readfirstlane(tk);   // SGPR base addressing
            tokp[p] = tk;
            const float* rowp = eproj + (size_t)tk * G3;
            xw0[p] = rowp[u];
            xw1[p] = rowp[u + 64];
            xw2[p] = rowp[u + 128];
            asm volatile("" : "+v"(xw0[p]), "+v"(xw1[p]), "+v"(xw2[p]));
        }
    };
    #pragma unroll
    for (int p = 0; p < 4; ++p) pref(p, p);

    float* outb = gru_out + (size_t)b * S_ * (2 * H_) + dir * H_ + u;

    for (int t = 0; t < S_; t += 4) {
        #pragma unroll
        for (int p = 0; p < 4; ++p) {
            const int tstep = t + p;
            const int tok   = tokp[p];
            const float x0 = xw0[p], x1 = xw1[p], x2 = xw2[p];

            // rec = h . U[:,col] for 3 columns; 4 indep fdot2 chains each
            const u32x4* h8 = (const u32x4*)s_h;
            float az[4] = {0,0,0,0}, ar_[4] = {0,0,0,0}, ac_[4] = {0,0,0,0};
            #pragma unroll
            for (int k = 0; k < 8; ++k) {
                const u32x4 hv = h8[k];
                const u32x4 vz = wz[k], vr = wr[k], vc = wc[k];
                az[0]  = fdot2_(hv.x, vz.x, az[0]);
                az[1]  = fdot2_(hv.y, vz.y, az[1]);
                az[2]  = fdot2_(hv.z, vz.z, az[2]);
                az[3]  = fdot2_(hv.w, vz.w, az[3]);
                ar_[0] = fdot2_(hv.x, vr.x, ar_[0]);
                ar_[1] = fdot2_(hv.y, vr.y, ar_[1]);
                ar_[2] = fdot2_(hv.z, vr.z, ar_[2]);
                ar_[3] = fdot2_(hv.w, vr.w, ar_[3]);
                ac_[0] = fdot2_(hv.x, vc.x, ac_[0]);
                ac_[1] = fdot2_(hv.y, vc.y, ac_[1]);
                ac_[2] = fdot2_(hv.z, vc.z, ac_[2]);
                ac_[3] = fdot2_(hv.w, vc.w, ac_[3]);
            }
            const float d0 = ((az[0]  + az[1])  + (az[2]  + az[3]))  + br0;
            const float d1 = ((ar_[0] + ar_[1]) + (ar_[2] + ar_[3])) + br1;
            const float d2 = ((ac_[0] + ac_[1]) + (ac_[2] + ac_[3])) + br2;

            const float z    = sigmoidf_(x0 + d0);
            const float r    = sigmoidf_(x1 + d1);
            const float hh   = tanh_fast(x2 + r * d2);
            const float hnew = z * hprev + (1.0f - z) * hh;
            const float res  = (tok != 0) ? hnew : hprev;   // mask_zero carry
            hprev = res;

            s_h[u] = (f16)res;
            __builtin_amdgcn_wave_barrier();   // keep write before next reads

            const int tt = dir ? (S_ - 1 - tstep) : tstep;
            outb[(size_t)tt * (2 * H_)] = res; // coalesced 256B store, no wait

            pref(tstep + 4, p);                // refill this prefetch slot
        }
    }
}

// x1 = sigmoid(gru_out @ w1 + b1), x2 = sigmoid(gru_out @ w2 + b2)
__global__ __launch_bounds__(256) void head_kernel(
    const float* __restrict__ gru,      // [B*S, 2H]
    const float* __restrict__ w1, const float* __restrict__ b1,
    const float* __restrict__ w2, const float* __restrict__ b2,
    float* __restrict__ x1, float* __restrict__ x2)
{
    __shared__ __align__(16) float s_w1[2 * H_];
    __shared__ __align__(16) float s_w2[2 * H_];
    const int tid = threadIdx.x;
    if (tid < 2 * H_)      s_w1[tid]          = w1[tid];
    else                   s_w2[tid - 2 * H_] = w2[tid - 2 * H_];
    __syncthreads();

    const int i = blockIdx.x * 256 + tid;
    const float4* g4 = (const float4*)(gru + (size_t)i * (2 * H_));
    float a1 = b1[0], a2 = b2[0];
    #pragma unroll
    for (int k = 0; k < (2 * H_) / 4; ++k) {
        const float4 v  = g4[k];
        const float4 q1 = ((const float4*)s_w1)[k];
        const float4 q2 = ((const float4*)s_w2)[k];
        a1 += v.x * q1.x + v.y * q1.y + v.z * q1.z + v.w * q1.w;
        a2 += v.x * q2.x + v.y * q2.y + v.z * q2.z + v.w * q2.w;
    }
    x1[i] = sigmoidf_(a1);
    x2[i] = sigmoidf_(a2);
}

extern "C" void kernel_launch(void* const* d_in, const int* in_sizes, int n_in,
                              void* d_out, int out_size, void* d_ws, size_t ws_size,
                              hipStream_t stream) {
    (void)in_sizes; (void)n_in; (void)ws_size; (void)out_size;

    const int*   inputs = (const int*)  d_in[0];
    const float* emb    = (const float*)d_in[1];
    const float* Wf     = (const float*)d_in[2];
    const float* Uf     = (const float*)d_in[3];
    const float* bif    = (const float*)d_in[4];
    const float* brf    = (const float*)d_in[5];
    const float* Wb     = (const float*)d_in[6];
    const float* Ub     = (const float*)d_in[7];
    const float* bib    = (const float*)d_in[8];
    const float* brb    = (const float*)d_in[9];
    const float* w1     = (const float*)d_in[10];
    const float* b1     = (const float*)d_in[11];
    const float* w2     = (const float*)d_in[12];
    const float* b2     = (const float*)d_in[13];

    float* out = (float*)d_out;
    float* x1  = out;                       // [B*S]
    float* x2  = out + (size_t)B_ * S_;     // [B*S]
    float* gru = out + (size_t)2 * B_ * S_; // [B*S, 2H]

    // workspace: proj [2][V][192] floats (7.67 MB), then Uh [2][192][32] u32 (48 KB)
    float* proj = (float*)d_ws;
    u32*   Uh   = (u32*)(proj + (size_t)2 * V_ * G3);

    proj_kernel<<<dim3((V_ + VCHUNK - 1) / VCHUNK, 2), 192, 0, stream>>>(
        emb, Wf, bif, Wb, bib, proj);
    upack_kernel<<<2, 256, 0, stream>>>(Uf, Ub, Uh);

    gru_scan6<<<B_ * 2, 64, 0, stream>>>(inputs, proj, Uh, brf, brb, gru);

    head_kernel<<<(B_ * S_) / 256, 256, 0, stream>>>(gru, w1, b1, w2, b2, x1, x2);
}

// Round 8
// 269.118 us; speedup vs baseline: 1.2757x; 1.2757x over previous
//
#include <hip/hip_runtime.h>
#include <hip/hip_bf16.h>
#include <hip/hip_fp16.h>

#define B_  128
#define S_  512
#define H_  64
#define E_  64
#define G3  192   // 3*H
#define V_  4996
#define VCHUNK 32

typedef float f32x2 __attribute__((ext_vector_type(2)));
typedef float f32x4 __attribute__((ext_vector_type(4)));
typedef unsigned int u32;
typedef u32 u32x4 __attribute__((ext_vector_type(4)));
typedef _Float16 f16;
typedef f16 f16x2 __attribute__((ext_vector_type(2)));

__device__ __forceinline__ float sigmoidf_(float x) {
    return 1.0f / (1.0f + __expf(-x));
}

__device__ __forceinline__ float tanh_fast(float x) {
    x = fminf(fmaxf(x, -15.0f), 15.0f);
    const float e = __expf(2.0f * x);
    return (e - 1.0f) / (e + 1.0f);
}

// D = a.x*b.x + a.y*b.y + c  (v_dot2_f32_f16)
__device__ __forceinline__ float fdot2_(u32 a, u32 b, float c) {
#if __has_builtin(__builtin_amdgcn_fdot2)
    return __builtin_amdgcn_fdot2(__builtin_bit_cast(f16x2, a),
                                  __builtin_bit_cast(f16x2, b), c, false);
#else
    const f16x2 av = __builtin_bit_cast(f16x2, a);
    const f16x2 bv = __builtin_bit_cast(f16x2, b);
    return fmaf((float)av.x, (float)bv.x, fmaf((float)av.y, (float)bv.y, c));
#endif
}

// ---------------------------------------------------------------------------
// Kernel 1: pre-project the embedding table through the input kernels (fp32).
//   proj[dir][v][j] = sum_e emb[v][e] * W_dir[e][j] + bi_dir[j]
// ---------------------------------------------------------------------------
__global__ __launch_bounds__(192) void proj_kernel(
    const float* __restrict__ emb,
    const float* __restrict__ Wf, const float* __restrict__ bif,
    const float* __restrict__ Wb, const float* __restrict__ bib,
    float* __restrict__ proj)            // [2][V][192]
{
    const int dir = blockIdx.y;
    const float* W  = dir ? Wb  : Wf;
    const float* bi = dir ? bib : bif;
    const int v0 = blockIdx.x * VCHUNK;
    const int j  = threadIdx.x;
    const int nrows = min(VCHUNK, V_ - v0);

    __shared__ __align__(16) float s_e[VCHUNK * E_];
    for (int i = j; i < nrows * E_; i += 192) s_e[i] = emb[(size_t)v0 * E_ + i];

    float wcol[E_];
    #pragma unroll
    for (int e = 0; e < E_; ++e) wcol[e] = W[e * G3 + j];
    const float bij = bi[j];
    __syncthreads();

    for (int r = 0; r < nrows; ++r) {
        const float4* x4 = (const float4*)(s_e + r * E_);
        float a0 = 0.f, a1 = 0.f, a2 = 0.f, a3 = 0.f;
        #pragma unroll
        for (int e4 = 0; e4 < 16; e4 += 4) {
            float4 h0 = x4[e4], h1 = x4[e4+1], h2 = x4[e4+2], h3 = x4[e4+3];
            a0 = fmaf(h0.x, wcol[4*e4+ 0], a0); a0 = fmaf(h0.y, wcol[4*e4+ 1], a0);
            a0 = fmaf(h0.z, wcol[4*e4+ 2], a0); a0 = fmaf(h0.w, wcol[4*e4+ 3], a0);
            a1 = fmaf(h1.x, wcol[4*e4+ 4], a1); a1 = fmaf(h1.y, wcol[4*e4+ 5], a1);
            a1 = fmaf(h1.z, wcol[4*e4+ 6], a1); a1 = fmaf(h1.w, wcol[4*e4+ 7], a1);
            a2 = fmaf(h2.x, wcol[4*e4+ 8], a2); a2 = fmaf(h2.y, wcol[4*e4+ 9], a2);
            a2 = fmaf(h2.z, wcol[4*e4+10], a2); a2 = fmaf(h2.w, wcol[4*e4+11], a2);
            a3 = fmaf(h3.x, wcol[4*e4+12], a3); a3 = fmaf(h3.y, wcol[4*e4+13], a3);
            a3 = fmaf(h3.z, wcol[4*e4+14], a3); a3 = fmaf(h3.w, wcol[4*e4+15], a3);
        }
        proj[((size_t)dir * V_ + v0 + r) * G3 + j] = ((a0 + a1) + (a2 + a3)) + bij;
    }
}

// Kernel 2: pack recurrent kernels to f16 pairs, column-major per gate column:
//   Uh[dir][j][kk] = pack_f16(U[2kk][j], U[2kk+1][j])   kk in [0,32)
__global__ void upack_kernel(const float* __restrict__ Uf,
                             const float* __restrict__ Ub,
                             u32* __restrict__ Uh)    // [2][192][32]
{
    const int dir = blockIdx.x;
    const float* U = dir ? Ub : Uf;
    u32* o = Uh + (size_t)dir * G3 * 32;
    for (int k = threadIdx.x; k < G3 * 32; k += blockDim.x) {
        const int j = k >> 5, kk = k & 31;
        f16x2 p;
        p.x = (f16)U[(2 * kk    ) * G3 + j];
        p.y = (f16)U[(2 * kk + 1) * G3 + j];
        o[(size_t)j * 32 + kk] = __builtin_bit_cast(u32, p);
    }
}

// ---------------------------------------------------------------------------
// Kernel 3: the sequential scan. ONE WAVE per (batch row, direction).
// Lane u owns unit u; all three gate columns (u, u+64, u+128) computed
// in-lane via v_dot2_f32_f16 against f16-packed U columns held in 96 pinned
// VGPRs. h lives in one 128-B f16 LDS row (8 broadcast ds_read_b128/step);
// outputs go straight to global (coalesced, never waited on). No barriers,
// no shuffles. xw prefetched 4 steps ahead into registers — NO pins on the
// prefetch (a register-tied asm right after the load forces vmcnt(0) at the
// asm site, which serialized R7 at ~1480 cyc/step).
// ---------------------------------------------------------------------------
__global__ __launch_bounds__(64)
__attribute__((amdgpu_waves_per_eu(1, 1)))
void gru_scan7(
    const int*   __restrict__ inputs,   // [B,S]
    const float* __restrict__ proj,     // [2][V][192]
    const u32*   __restrict__ Uh,       // [2][192][32] f16-pairs
    const float* __restrict__ brf, const float* __restrict__ brb,
    float* __restrict__ gru_out)        // [B,S,2H]
{
    const int b   = blockIdx.x >> 1;
    const int dir = blockIdx.x & 1;
    const int u   = threadIdx.x;           // == unit

    const float* eproj = proj + (size_t)dir * V_ * G3;
    const float* br    = dir ? brb : brf;

    __shared__ int s_idx[S_];
    __shared__ __align__(16) f16 s_h[H_];  // single row; same-wave DS is in-order

    for (int t = u; t < S_; t += 64) s_idx[t] = inputs[b * S_ + t];
    s_h[u] = (f16)0.0f;
    __builtin_amdgcn_wave_barrier();       // compiler ordering only, no HW cost

    // f16-packed U columns: 3 x 8 x u32x4 = 96 VGPRs, pinned (asm-defined =>
    // non-rematerializable; small enough to never spill).
    u32x4 wz[8], wr[8], wc[8];
    {
        const u32x4* pz = (const u32x4*)(Uh + ((size_t)dir * G3 + u      ) * 32);
        const u32x4* pr = (const u32x4*)(Uh + ((size_t)dir * G3 + u + 64 ) * 32);
        const u32x4* pc = (const u32x4*)(Uh + ((size_t)dir * G3 + u + 128) * 32);
        #pragma unroll
        for (int k = 0; k < 8; ++k) { wz[k] = pz[k]; wr[k] = pr[k]; wc[k] = pc[k]; }
        #pragma unroll
        for (int k = 0; k < 8; ++k) {
            asm volatile("" : "+v"(wz[k]));
            asm volatile("" : "+v"(wr[k]));
            asm volatile("" : "+v"(wc[k]));
        }
    }
    const float br0 = br[u], br1 = br[u + 64], br2 = br[u + 128];
    float hprev = 0.0f;

    // 4-step-ahead xw prefetch straight into registers (unrolled rotation).
    // NOTE: no pins here — let the waitcnt land at the use, 4 steps later.
    float xw0[4], xw1[4], xw2[4];
    int   tokp[4];
    auto pref = [&](int tstep, int p) {
        if (tstep < S_) {
            const int tt = dir ? (S_ - 1 - tstep) : tstep;
            int tk = s_idx[tt];
            tk = __builtin_amdgcn_readfirstlane(tk);   // SGPR base addressing
            tokp[p] = tk;
            const float* rowp = eproj + (size_t)tk * G3;
            xw0[p] = rowp[u];
            xw1[p] = rowp[u + 64];
            xw2[p] = rowp[u + 128];
        }
    };
    #pragma unroll
    for (int p = 0; p < 4; ++p) pref(p, p);

    float* outb = gru_out + (size_t)b * S_ * (2 * H_) + dir * H_ + u;

    for (int t = 0; t < S_; t += 4) {
        #pragma unroll
        for (int p = 0; p < 4; ++p) {
            const int tstep = t + p;
            const int tok   = tokp[p];
            const float x0 = xw0[p], x1 = xw1[p], x2 = xw2[p];

            // rec = h . U[:,col] for 3 columns; 4 indep fdot2 chains each
            const u32x4* h8 = (const u32x4*)s_h;
            float az[4] = {0,0,0,0}, ar_[4] = {0,0,0,0}, ac_[4] = {0,0,0,0};
            #pragma unroll
            for (int k = 0; k < 8; ++k) {
                const u32x4 hv = h8[k];
                const u32x4 vz = wz[k], vr = wr[k], vc = wc[k];
                az[0]  = fdot2_(hv.x, vz.x, az[0]);
                az[1]  = fdot2_(hv.y, vz.y, az[1]);
                az[2]  = fdot2_(hv.z, vz.z, az[2]);
                az[3]  = fdot2_(hv.w, vz.w, az[3]);
                ar_[0] = fdot2_(hv.x, vr.x, ar_[0]);
                ar_[1] = fdot2_(hv.y, vr.y, ar_[1]);
                ar_[2] = fdot2_(hv.z, vr.z, ar_[2]);
                ar_[3] = fdot2_(hv.w, vr.w, ar_[3]);
                ac_[0] = fdot2_(hv.x, vc.x, ac_[0]);
                ac_[1] = fdot2_(hv.y, vc.y, ac_[1]);
                ac_[2] = fdot2_(hv.z, vc.z, ac_[2]);
                ac_[3] = fdot2_(hv.w, vc.w, ac_[3]);
            }
            const float d0 = ((az[0]  + az[1])  + (az[2]  + az[3]))  + br0;
            const float d1 = ((ar_[0] + ar_[1]) + (ar_[2] + ar_[3])) + br1;
            const float d2 = ((ac_[0] + ac_[1]) + (ac_[2] + ac_[3])) + br2;

            const float z    = sigmoidf_(x0 + d0);
            const float r    = sigmoidf_(x1 + d1);
            const float hh   = tanh_fast(x2 + r * d2);
            const float hnew = z * hprev + (1.0f - z) * hh;
            const float res  = (tok != 0) ? hnew : hprev;   // mask_zero carry
            hprev = res;

            s_h[u] = (f16)res;
            __builtin_amdgcn_wave_barrier();   // keep write before next reads

            const int tt = dir ? (S_ - 1 - tstep) : tstep;
            outb[(size_t)tt * (2 * H_)] = res; // coalesced 256B store, no wait

            pref(tstep + 4, p);                // refill this prefetch slot
        }
    }
}

// x1 = sigmoid(gru_out @ w1 + b1), x2 = sigmoid(gru_out @ w2 + b2)
__global__ __launch_bounds__(256) void head_kernel(
    const float* __restrict__ gru,      // [B*S, 2H]
    const float* __restrict__ w1, const float* __restrict__ b1,
    const float* __restrict__ w2, const float* __restrict__ b2,
    float* __restrict__ x1, float* __restrict__ x2)
{
    __shared__ __align__(16) float s_w1[2 * H_];
    __shared__ __align__(16) float s_w2[2 * H_];
    const int tid = threadIdx.x;
    if (tid < 2 * H_)      s_w1[tid]          = w1[tid];
    else                   s_w2[tid - 2 * H_] = w2[tid - 2 * H_];
    __syncthreads();

    const int i = blockIdx.x * 256 + tid;
    const float4* g4 = (const float4*)(gru + (size_t)i * (2 * H_));
    float a1 = b1[0], a2 = b2[0];
    #pragma unroll
    for (int k = 0; k < (2 * H_) / 4; ++k) {
        const float4 v  = g4[k];
        const float4 q1 = ((const float4*)s_w1)[k];
        const float4 q2 = ((const float4*)s_w2)[k];
        a1 += v.x * q1.x + v.y * q1.y + v.z * q1.z + v.w * q1.w;
        a2 += v.x * q2.x + v.y * q2.y + v.z * q2.z + v.w * q2.w;
    }
    x1[i] = sigmoidf_(a1);
    x2[i] = sigmoidf_(a2);
}

extern "C" void kernel_launch(void* const* d_in, const int* in_sizes, int n_in,
                              void* d_out, int out_size, void* d_ws, size_t ws_size,
                              hipStream_t stream) {
    (void)in_sizes; (void)n_in; (void)ws_size; (void)out_size;

    const int*   inputs = (const int*)  d_in[0];
    const float* emb    = (const float*)d_in[1];
    const float* Wf     = (const float*)d_in[2];
    const float* Uf     = (const float*)d_in[3];
    const float* bif    = (const float*)d_in[4];
    const float* brf    = (const float*)d_in[5];
    const float* Wb     = (const float*)d_in[6];
    const float* Ub     = (const float*)d_in[7];
    const float* bib    = (const float*)d_in[8];
    const float* brb    = (const float*)d_in[9];
    const float* w1     = (const float*)d_in[10];
    const float* b1     = (const float*)d_in[11];
    const float* w2     = (const float*)d_in[12];
    const float* b2     = (const float*)d_in[13];

    float* out = (float*)d_out;
    float* x1  = out;                       // [B*S]
    float* x2  = out + (size_t)B_ * S_;     // [B*S]
    float* gru = out + (size_t)2 * B_ * S_; // [B*S, 2H]

    // workspace: proj [2][V][192] floats (7.67 MB), then Uh [2][192][32] u32 (48 KB)
    float* proj = (float*)d_ws;
    u32*   Uh   = (u32*)(proj + (size_t)2 * V_ * G3);

    proj_kernel<<<dim3((V_ + VCHUNK - 1) / VCHUNK, 2), 192, 0, stream>>>(
        emb, Wf, bif, Wb, bib, proj);
    upack_kernel<<<2, 256, 0, stream>>>(Uf, Ub, Uh);

    gru_scan7<<<B_ * 2, 64, 0, stream>>>(inputs, proj, Uh, brf, brb, gru);

    head_kernel<<<(B_ * S_) / 256, 256, 0, stream>>>(gru, w1, b1, w2, b2, x1, x2);
}

// Round 9
// 237.322 us; speedup vs baseline: 1.4466x; 1.1340x over previous
//
#include <hip/hip_runtime.h>
#include <hip/hip_bf16.h>
#include <hip/hip_fp16.h>

#define B_  128
#define S_  512
#define H_  64
#define E_  64
#define G3  192   // 3*H
#define V_  4996
#define VCHUNK 32
#define STOK  520   // padded scan-ordered token array (130 groups of 4)

typedef float f32x4 __attribute__((ext_vector_type(4)));
typedef unsigned int u32;
typedef u32 u32x4 __attribute__((ext_vector_type(4)));
typedef int i32x4 __attribute__((ext_vector_type(4)));
typedef _Float16 f16;
typedef f16 f16x2 __attribute__((ext_vector_type(2)));

__device__ __forceinline__ float sigmoidf_(float x) {
    return 1.0f / (1.0f + __expf(-x));
}

__device__ __forceinline__ float tanh_fast(float x) {
    x = fminf(fmaxf(x, -15.0f), 15.0f);
    const float e = __expf(2.0f * x);
    return (e - 1.0f) / (e + 1.0f);
}

// D = a.x*b.x + a.y*b.y + c  (v_dot2_f32_f16)
__device__ __forceinline__ float fdot2_(u32 a, u32 b, float c) {
#if __has_builtin(__builtin_amdgcn_fdot2)
    return __builtin_amdgcn_fdot2(__builtin_bit_cast(f16x2, a),
                                  __builtin_bit_cast(f16x2, b), c, false);
#else
    const f16x2 av = __builtin_bit_cast(f16x2, a);
    const f16x2 bv = __builtin_bit_cast(f16x2, b);
    return fmaf((float)av.x, (float)bv.x, fmaf((float)av.y, (float)bv.y, c));
#endif
}

// ---------------------------------------------------------------------------
// Kernel 1: pre-project the embedding table through the input kernels (fp32).
//   proj[dir][v][j] = sum_e emb[v][e] * W_dir[e][j] + bi_dir[j]
// ---------------------------------------------------------------------------
__global__ __launch_bounds__(192) void proj_kernel(
    const float* __restrict__ emb,
    const float* __restrict__ Wf, const float* __restrict__ bif,
    const float* __restrict__ Wb, const float* __restrict__ bib,
    float* __restrict__ proj)            // [2][V][192]
{
    const int dir = blockIdx.y;
    const float* W  = dir ? Wb  : Wf;
    const float* bi = dir ? bib : bif;
    const int v0 = blockIdx.x * VCHUNK;
    const int j  = threadIdx.x;
    const int nrows = min(VCHUNK, V_ - v0);

    __shared__ __align__(16) float s_e[VCHUNK * E_];
    for (int i = j; i < nrows * E_; i += 192) s_e[i] = emb[(size_t)v0 * E_ + i];

    float wcol[E_];
    #pragma unroll
    for (int e = 0; e < E_; ++e) wcol[e] = W[e * G3 + j];
    const float bij = bi[j];
    __syncthreads();

    for (int r = 0; r < nrows; ++r) {
        const float4* x4 = (const float4*)(s_e + r * E_);
        float a0 = 0.f, a1 = 0.f, a2 = 0.f, a3 = 0.f;
        #pragma unroll
        for (int e4 = 0; e4 < 16; e4 += 4) {
            float4 h0 = x4[e4], h1 = x4[e4+1], h2 = x4[e4+2], h3 = x4[e4+3];
            a0 = fmaf(h0.x, wcol[4*e4+ 0], a0); a0 = fmaf(h0.y, wcol[4*e4+ 1], a0);
            a0 = fmaf(h0.z, wcol[4*e4+ 2], a0); a0 = fmaf(h0.w, wcol[4*e4+ 3], a0);
            a1 = fmaf(h1.x, wcol[4*e4+ 4], a1); a1 = fmaf(h1.y, wcol[4*e4+ 5], a1);
            a1 = fmaf(h1.z, wcol[4*e4+ 6], a1); a1 = fmaf(h1.w, wcol[4*e4+ 7], a1);
            a2 = fmaf(h2.x, wcol[4*e4+ 8], a2); a2 = fmaf(h2.y, wcol[4*e4+ 9], a2);
            a2 = fmaf(h2.z, wcol[4*e4+10], a2); a2 = fmaf(h2.w, wcol[4*e4+11], a2);
            a3 = fmaf(h3.x, wcol[4*e4+12], a3); a3 = fmaf(h3.y, wcol[4*e4+13], a3);
            a3 = fmaf(h3.z, wcol[4*e4+14], a3); a3 = fmaf(h3.w, wcol[4*e4+15], a3);
        }
        proj[((size_t)dir * V_ + v0 + r) * G3 + j] = ((a0 + a1) + (a2 + a3)) + bij;
    }
}

// Kernel 2: pack recurrent kernels to f16 pairs, column-major per gate column:
//   Uh[dir][j][kk] = pack_f16(U[2kk][j], U[2kk+1][j])   kk in [0,32)
__global__ void upack_kernel(const float* __restrict__ Uf,
                             const float* __restrict__ Ub,
                             u32* __restrict__ Uh)    // [2][192][32]
{
    const int dir = blockIdx.x;
    const float* U = dir ? Ub : Uf;
    u32* o = Uh + (size_t)dir * G3 * 32;
    for (int k = threadIdx.x; k < G3 * 32; k += blockDim.x) {
        const int j = k >> 5, kk = k & 31;
        f16x2 p;
        p.x = (f16)U[(2 * kk    ) * G3 + j];
        p.y = (f16)U[(2 * kk + 1) * G3 + j];
        o[(size_t)j * 32 + kk] = __builtin_bit_cast(u32, p);
    }
}

// ---------------------------------------------------------------------------
// Kernel 3: the sequential scan. ONE WAVE per (batch row, direction).
// Lane u owns unit u; all three gate columns (u, u+64, u+128) computed
// in-lane via v_dot2_f32_f16 against f16-packed U columns in 96 pinned VGPRs.
// h lives in one 128-B f16 LDS row. All waits statically precise:
//  - tokens pre-reordered into scan order (padded to 520), fetched as
//    broadcast int4 one 4-step GROUP ahead (lgkm wait subsumed by h-reads);
//  - xw prefetch 4 steps ahead, UNCONDITIONAL (no branch -> no conservative
//    vmcnt merge, which serialized R8 at ~1140 cyc/step);
//  - outputs stored directly, never waited on. No barriers, no shuffles.
// ---------------------------------------------------------------------------
__global__ __launch_bounds__(64)
__attribute__((amdgpu_waves_per_eu(1, 1)))
void gru_scan8(
    const int*   __restrict__ inputs,   // [B,S]
    const float* __restrict__ proj,     // [2][V][192]
    const u32*   __restrict__ Uh,       // [2][192][32] f16-pairs
    const float* __restrict__ brf, const float* __restrict__ brb,
    float* __restrict__ gru_out)        // [B,S,2H]
{
    const int b   = blockIdx.x >> 1;
    const int dir = blockIdx.x & 1;
    const int u   = threadIdx.x;           // == unit

    const float* eproj = proj + (size_t)dir * V_ * G3;
    const float* br    = dir ? brb : brf;

    __shared__ __align__(16) int s_tok[STOK];   // scan-ordered tokens + pad
    __shared__ __align__(16) f16 s_h[H_];

    for (int t = u; t < S_; t += 64)
        s_tok[t] = inputs[b * S_ + (dir ? (S_ - 1 - t) : t)];
    for (int t = S_ + u; t < STOK; t += 64) s_tok[t] = 0;   // pad -> row 0
    s_h[u] = (f16)0.0f;
    __builtin_amdgcn_wave_barrier();

    // f16-packed U columns: 3 x 8 x u32x4 = 96 VGPRs, pinned.
    u32x4 wz[8], wr[8], wc[8];
    {
        const u32x4* pz = (const u32x4*)(Uh + ((size_t)dir * G3 + u      ) * 32);
        const u32x4* pr = (const u32x4*)(Uh + ((size_t)dir * G3 + u + 64 ) * 32);
        const u32x4* pc = (const u32x4*)(Uh + ((size_t)dir * G3 + u + 128) * 32);
        #pragma unroll
        for (int k = 0; k < 8; ++k) { wz[k] = pz[k]; wr[k] = pr[k]; wc[k] = pc[k]; }
        #pragma unroll
        for (int k = 0; k < 8; ++k) {
            asm volatile("" : "+v"(wz[k]));
            asm volatile("" : "+v"(wr[k]));
            asm volatile("" : "+v"(wc[k]));
        }
    }
    const float br0 = br[u], br1 = br[u + 64], br2 = br[u + 128];
    float hprev = 0.0f;

    // xw prefetch registers, 4 steps (one group) ahead. No branches, no pins.
    float xw0[4], xw1[4], xw2[4];
    int   tokp[4];
    auto pref = [&](int tk, int p) {      // tk: scalar token (readfirstlane'd)
        const float* rowp = eproj + (size_t)tk * G3;
        xw0[p] = rowp[u];
        xw1[p] = rowp[u + 64];
        xw2[p] = rowp[u + 128];
    };

    const i32x4* tg4 = (const i32x4*)s_tok;   // broadcast group reads

    // Prologue: group 0 -> slots, group 1 staged for prefetch during group 0.
    i32x4 tg0 = tg4[0];
    i32x4 tgP = tg4[1];
    #pragma unroll
    for (int p = 0; p < 4; ++p) {
        const int tk = __builtin_amdgcn_readfirstlane(tg0[p]);
        tokp[p] = tk;
        pref(tk, p);
    }

    float* outb = gru_out + (size_t)b * S_ * (2 * H_) + dir * H_ + u;

    for (int g = 0; g < S_ / 4; ++g) {
        // stage tokens for group g+2 (clamped into the padded array)
        const int gn = (g + 2 < STOK / 4) ? (g + 2) : (STOK / 4 - 1);
        i32x4 tgN = tg4[gn];

        #pragma unroll
        for (int p = 0; p < 4; ++p) {
            const int tstep = 4 * g + p;
            const int tok   = tokp[p];
            const float x0 = xw0[p], x1 = xw1[p], x2 = xw2[p];

            // rec = h . U[:,col] for 3 columns; 4 indep fdot2 chains each
            const u32x4* h8 = (const u32x4*)s_h;
            float az[4] = {0,0,0,0}, ar_[4] = {0,0,0,0}, ac_[4] = {0,0,0,0};
            #pragma unroll
            for (int k = 0; k < 8; ++k) {
                const u32x4 hv = h8[k];
                const u32x4 vz = wz[k], vr = wr[k], vc = wc[k];
                az[0]  = fdot2_(hv.x, vz.x, az[0]);
                az[1]  = fdot2_(hv.y, vz.y, az[1]);
                az[2]  = fdot2_(hv.z, vz.z, az[2]);
                az[3]  = fdot2_(hv.w, vz.w, az[3]);
                ar_[0] = fdot2_(hv.x, vr.x, ar_[0]);
                ar_[1] = fdot2_(hv.y, vr.y, ar_[1]);
                ar_[2] = fdot2_(hv.z, vr.z, ar_[2]);
                ar_[3] = fdot2_(hv.w, vr.w, ar_[3]);
                ac_[0] = fdot2_(hv.x, vc.x, ac_[0]);
                ac_[1] = fdot2_(hv.y, vc.y, ac_[1]);
                ac_[2] = fdot2_(hv.z, vc.z, ac_[2]);
                ac_[3] = fdot2_(hv.w, vc.w, ac_[3]);
            }
            const float d0 = ((az[0]  + az[1])  + (az[2]  + az[3]))  + br0;
            const float d1 = ((ar_[0] + ar_[1]) + (ar_[2] + ar_[3])) + br1;
            const float d2 = ((ac_[0] + ac_[1]) + (ac_[2] + ac_[3])) + br2;

            const float z    = sigmoidf_(x0 + d0);
            const float r    = sigmoidf_(x1 + d1);
            const float hh   = tanh_fast(x2 + r * d2);
            const float hnew = z * hprev + (1.0f - z) * hh;
            const float res  = (tok != 0) ? hnew : hprev;   // mask_zero carry
            hprev = res;

            s_h[u] = (f16)res;
            __builtin_amdgcn_wave_barrier();   // keep write before next reads

            const int tt = dir ? (S_ - 1 - tstep) : tstep;
            outb[(size_t)tt * (2 * H_)] = res; // coalesced 256B store, no wait

            // refill slot p for step tstep+4 (token from staged group, no LDS
            // wait on the critical path; load unconditional -> precise vmcnt)
            const int tk = __builtin_amdgcn_readfirstlane(tgP[p]);
            tokp[p] = tk;
            pref(tk, p);
        }
        tgP = tgN;
    }
}

// x1 = sigmoid(gru_out @ w1 + b1), x2 = sigmoid(gru_out @ w2 + b2)
__global__ __launch_bounds__(256) void head_kernel(
    const float* __restrict__ gru,      // [B*S, 2H]
    const float* __restrict__ w1, const float* __restrict__ b1,
    const float* __restrict__ w2, const float* __restrict__ b2,
    float* __restrict__ x1, float* __restrict__ x2)
{
    __shared__ __align__(16) float s_w1[2 * H_];
    __shared__ __align__(16) float s_w2[2 * H_];
    const int tid = threadIdx.x;
    if (tid < 2 * H_)      s_w1[tid]          = w1[tid];
    else                   s_w2[tid - 2 * H_] = w2[tid - 2 * H_];
    __syncthreads();

    const int i = blockIdx.x * 256 + tid;
    const float4* g4 = (const float4*)(gru + (size_t)i * (2 * H_));
    float a1 = b1[0], a2 = b2[0];
    #pragma unroll
    for (int k = 0; k < (2 * H_) / 4; ++k) {
        const float4 v  = g4[k];
        const float4 q1 = ((const float4*)s_w1)[k];
        const float4 q2 = ((const float4*)s_w2)[k];
        a1 += v.x * q1.x + v.y * q1.y + v.z * q1.z + v.w * q1.w;
        a2 += v.x * q2.x + v.y * q2.y + v.z * q2.z + v.w * q2.w;
    }
    x1[i] = sigmoidf_(a1);
    x2[i] = sigmoidf_(a2);
}

extern "C" void kernel_launch(void* const* d_in, const int* in_sizes, int n_in,
                              void* d_out, int out_size, void* d_ws, size_t ws_size,
                              hipStream_t stream) {
    (void)in_sizes; (void)n_in; (void)ws_size; (void)out_size;

    const int*   inputs = (const int*)  d_in[0];
    const float* emb    = (const float*)d_in[1];
    const float* Wf     = (const float*)d_in[2];
    const float* Uf     = (const float*)d_in[3];
    const float* bif    = (const float*)d_in[4];
    const float* brf    = (const float*)d_in[5];
    const float* Wb     = (const float*)d_in[6];
    const float* Ub     = (const float*)d_in[7];
    const float* bib    = (const float*)d_in[8];
    const float* brb    = (const float*)d_in[9];
    const float* w1     = (const float*)d_in[10];
    const float* b1     = (const float*)d_in[11];
    const float* w2     = (const float*)d_in[12];
    const float* b2     = (const float*)d_in[13];

    float* out = (float*)d_out;
    float* x1  = out;                       // [B*S]
    float* x2  = out + (size_t)B_ * S_;     // [B*S]
    float* gru = out + (size_t)2 * B_ * S_; // [B*S, 2H]

    // workspace: proj [2][V][192] floats (7.67 MB), then Uh [2][192][32] u32 (48 KB)
    float* proj = (float*)d_ws;
    u32*   Uh   = (u32*)(proj + (size_t)2 * V_ * G3);

    proj_kernel<<<dim3((V_ + VCHUNK - 1) / VCHUNK, 2), 192, 0, stream>>>(
        emb, Wf, bif, Wb, bib, proj);
    upack_kernel<<<2, 256, 0, stream>>>(Uf, Ub, Uh);

    gru_scan8<<<B_ * 2, 64, 0, stream>>>(inputs, proj, Uh, brf, brb, gru);

    head_kernel<<<(B_ * S_) / 256, 256, 0, stream>>>(gru, w1, b1, w2, b2, x1, x2);
}

// Round 10
// 235.774 us; speedup vs baseline: 1.4561x; 1.0066x over previous
//
#include <hip/hip_runtime.h>
#include <hip/hip_bf16.h>
#include <hip/hip_fp16.h>

#define B_  128
#define S_  512
#define H_  64
#define E_  64
#define G3  192   // 3*H
#define V_  4996
#define VCHUNK 32
#define CHUNK  16            // steps per LDS xw chunk
#define NCHUNK (S_ / CHUNK)  // 32
#define STOK  (S_ + CHUNK)   // scan-ordered tokens + one pad chunk

typedef float f32x4 __attribute__((ext_vector_type(4)));
typedef unsigned int u32;
typedef u32 u32x4 __attribute__((ext_vector_type(4)));
typedef _Float16 f16;
typedef f16 f16x2 __attribute__((ext_vector_type(2)));

__device__ __forceinline__ float fast_rcp(float x) {
#if __has_builtin(__builtin_amdgcn_rcpf)
    return __builtin_amdgcn_rcpf(x);
#else
    return 1.0f / x;
#endif
}
__device__ __forceinline__ float fast_exp(float x) {   // e^x
#if __has_builtin(__builtin_amdgcn_exp2f)
    return __builtin_amdgcn_exp2f(x * 1.44269504f);
#else
    return __expf(x);
#endif
}
__device__ __forceinline__ float sigmoidf_(float x) {
    return fast_rcp(1.0f + fast_exp(-x));              // saturates cleanly
}
__device__ __forceinline__ float tanh_fast(float x) {
    return 1.0f - 2.0f * fast_rcp(1.0f + fast_exp(2.0f * x));
}

// D = a.x*b.x + a.y*b.y + c  (v_dot2_f32_f16)
__device__ __forceinline__ float fdot2_(u32 a, u32 b, float c) {
#if __has_builtin(__builtin_amdgcn_fdot2)
    return __builtin_amdgcn_fdot2(__builtin_bit_cast(f16x2, a),
                                  __builtin_bit_cast(f16x2, b), c, false);
#else
    const f16x2 av = __builtin_bit_cast(f16x2, a);
    const f16x2 bv = __builtin_bit_cast(f16x2, b);
    return fmaf((float)av.x, (float)bv.x, fmaf((float)av.y, (float)bv.y, c));
#endif
}

// ---------------------------------------------------------------------------
// Kernel 1: pre-project the embedding table through the input kernels (fp32).
//   proj[dir][v][j] = sum_e emb[v][e] * W_dir[e][j] + bi_dir[j]
// ---------------------------------------------------------------------------
__global__ __launch_bounds__(192) void proj_kernel(
    const float* __restrict__ emb,
    const float* __restrict__ Wf, const float* __restrict__ bif,
    const float* __restrict__ Wb, const float* __restrict__ bib,
    float* __restrict__ proj)            // [2][V][192]
{
    const int dir = blockIdx.y;
    const float* W  = dir ? Wb  : Wf;
    const float* bi = dir ? bib : bif;
    const int v0 = blockIdx.x * VCHUNK;
    const int j  = threadIdx.x;
    const int nrows = min(VCHUNK, V_ - v0);

    __shared__ __align__(16) float s_e[VCHUNK * E_];
    for (int i = j; i < nrows * E_; i += 192) s_e[i] = emb[(size_t)v0 * E_ + i];

    float wcol[E_];
    #pragma unroll
    for (int e = 0; e < E_; ++e) wcol[e] = W[e * G3 + j];
    const float bij = bi[j];
    __syncthreads();

    for (int r = 0; r < nrows; ++r) {
        const float4* x4 = (const float4*)(s_e + r * E_);
        float a0 = 0.f, a1 = 0.f, a2 = 0.f, a3 = 0.f;
        #pragma unroll
        for (int e4 = 0; e4 < 16; e4 += 4) {
            float4 h0 = x4[e4], h1 = x4[e4+1], h2 = x4[e4+2], h3 = x4[e4+3];
            a0 = fmaf(h0.x, wcol[4*e4+ 0], a0); a0 = fmaf(h0.y, wcol[4*e4+ 1], a0);
            a0 = fmaf(h0.z, wcol[4*e4+ 2], a0); a0 = fmaf(h0.w, wcol[4*e4+ 3], a0);
            a1 = fmaf(h1.x, wcol[4*e4+ 4], a1); a1 = fmaf(h1.y, wcol[4*e4+ 5], a1);
            a1 = fmaf(h1.z, wcol[4*e4+ 6], a1); a1 = fmaf(h1.w, wcol[4*e4+ 7], a1);
            a2 = fmaf(h2.x, wcol[4*e4+ 8], a2); a2 = fmaf(h2.y, wcol[4*e4+ 9], a2);
            a2 = fmaf(h2.z, wcol[4*e4+10], a2); a2 = fmaf(h2.w, wcol[4*e4+11], a2);
            a3 = fmaf(h3.x, wcol[4*e4+12], a3); a3 = fmaf(h3.y, wcol[4*e4+13], a3);
            a3 = fmaf(h3.z, wcol[4*e4+14], a3); a3 = fmaf(h3.w, wcol[4*e4+15], a3);
        }
        proj[((size_t)dir * V_ + v0 + r) * G3 + j] = ((a0 + a1) + (a2 + a3)) + bij;
    }
}

// Kernel 2: pack recurrent kernels to f16 pairs, column-major per gate column:
//   Uh[dir][j][kk] = pack_f16(U[2kk][j], U[2kk+1][j])   kk in [0,32)
__global__ void upack_kernel(const float* __restrict__ Uf,
                             const float* __restrict__ Ub,
                             u32* __restrict__ Uh)    // [2][192][32]
{
    const int dir = blockIdx.x;
    const float* U = dir ? Ub : Uf;
    u32* o = Uh + (size_t)dir * G3 * 32;
    for (int k = threadIdx.x; k < G3 * 32; k += blockDim.x) {
        const int j = k >> 5, kk = k & 31;
        f16x2 p;
        p.x = (f16)U[(2 * kk    ) * G3 + j];
        p.y = (f16)U[(2 * kk + 1) * G3 + j];
        o[(size_t)j * 32 + kk] = __builtin_bit_cast(u32, p);
    }
}

// ---------------------------------------------------------------------------
// Kernel 3: the sequential scan. ONE WAVE per (batch row, direction).
// Lane u owns unit u; gate columns (u, u+64, u+128) in-lane via fdot2 against
// f16 U columns in 96 pinned VGPRs. Steady-state steps touch ONLY LDS+VALU:
// xw comes from a 16-step LDS chunk, reg-staged with a T14 split (issue 12
// f32x4 global loads at chunk start for chunk c+1 -> hold in 48 VGPRs ->
// vmcnt wait + 12 ds_write_b128 at chunk end). The per-step vmem wait that
// bounded R9 (~990 cyc/step at 17.8% VALUBusy) is gone; only the never-waited
// output store touches vmem inside a step.
// ---------------------------------------------------------------------------
__global__ __launch_bounds__(64)
__attribute__((amdgpu_waves_per_eu(1, 1)))
void gru_scan9(
    const int*   __restrict__ inputs,   // [B,S]
    const float* __restrict__ proj,     // [2][V][192]
    const u32*   __restrict__ Uh,       // [2][192][32] f16-pairs
    const float* __restrict__ brf, const float* __restrict__ brb,
    float* __restrict__ gru_out)        // [B,S,2H]
{
    const int b   = blockIdx.x >> 1;
    const int dir = blockIdx.x & 1;
    const int u   = threadIdx.x;           // == unit

    const float* eproj = proj + (size_t)dir * V_ * G3;
    const float* br    = dir ? brb : brf;

    __shared__ __align__(16) int   s_tok[STOK];          // scan order + pad
    __shared__ __align__(16) f16   s_h[H_];
    __shared__ __align__(16) float s_xw[2][CHUNK * G3];  // 2 x 12 KB

    for (int t = u; t < S_; t += 64)
        s_tok[t] = inputs[b * S_ + (dir ? (S_ - 1 - t) : t)];
    for (int t = S_ + u; t < STOK; t += 64) s_tok[t] = 0;  // pad -> row 0
    s_h[u] = (f16)0.0f;
    __builtin_amdgcn_wave_barrier();

    // f16-packed U columns: 3 x 8 x u32x4 = 96 VGPRs, pinned.
    u32x4 wz[8], wr[8], wc[8];
    {
        const u32x4* pz = (const u32x4*)(Uh + ((size_t)dir * G3 + u      ) * 32);
        const u32x4* pr = (const u32x4*)(Uh + ((size_t)dir * G3 + u + 64 ) * 32);
        const u32x4* pc = (const u32x4*)(Uh + ((size_t)dir * G3 + u + 128) * 32);
        #pragma unroll
        for (int k = 0; k < 8; ++k) { wz[k] = pz[k]; wr[k] = pr[k]; wc[k] = pc[k]; }
        #pragma unroll
        for (int k = 0; k < 8; ++k) {
            asm volatile("" : "+v"(wz[k]));
            asm volatile("" : "+v"(wr[k]));
            asm volatile("" : "+v"(wc[k]));
        }
    }
    const float br0 = br[u], br1 = br[u + 64], br2 = br[u + 128];
    float hprev = 0.0f;

    // ---- chunk staging: 12 x f32x4 per lane = one 16-step chunk ----------
    f32x4 ld[12];
    auto stage_issue = [&](int baseStep) {   // gather chunk into registers
        #pragma unroll
        for (int i = 0; i < 12; ++i) {
            const int idx = i * 64 + u;      // 16B slot in chunk (0..767)
            const int row = idx / 48;        // 48 slots per 192-float row
            const int off = idx - row * 48;
            const int tk  = s_tok[baseStep + row];
            ld[i] = *(const f32x4*)(eproj + (size_t)tk * G3 + off * 4);
        }
    };
    auto stage_write = [&](int nbuf) {       // publish to LDS (after vm wait)
        #pragma unroll
        for (int i = 0; i < 12; ++i) {
            const int idx = i * 64 + u;
            *(f32x4*)(&s_xw[nbuf][idx * 4]) = ld[i];
        }
    };

    stage_issue(0);
    stage_write(0);                           // chunk 0 ready (single wave)
    __builtin_amdgcn_wave_barrier();

    float* outb = gru_out + (size_t)b * S_ * (2 * H_) + dir * H_ + u;

    for (int c = 0; c < NCHUNK; ++c) {
        const int buf = c & 1;
        stage_issue((c + 1) * CHUNK);         // loads for next chunk (pad-safe)

        #pragma unroll 1                      // keep stage loads hoisted at top
        for (int t0 = 0; t0 < CHUNK; ++t0) {
            const int t = c * CHUNK + t0;

            const int   tok = s_tok[t];                       // broadcast b32
            const float x0  = s_xw[buf][t0 * G3 + u];
            const float x1  = s_xw[buf][t0 * G3 + u + 64];
            const float x2  = s_xw[buf][t0 * G3 + u + 128];

            // rec = h . U[:,col] for 3 columns; 4 indep fdot2 chains each
            const u32x4* h8 = (const u32x4*)s_h;
            float az[4] = {0,0,0,0}, ar_[4] = {0,0,0,0}, ac_[4] = {0,0,0,0};
            #pragma unroll
            for (int k = 0; k < 8; ++k) {
                const u32x4 hv = h8[k];
                const u32x4 vz = wz[k], vr = wr[k], vc = wc[k];
                az[0]  = fdot2_(hv.x, vz.x, az[0]);
                az[1]  = fdot2_(hv.y, vz.y, az[1]);
                az[2]  = fdot2_(hv.z, vz.z, az[2]);
                az[3]  = fdot2_(hv.w, vz.w, az[3]);
                ar_[0] = fdot2_(hv.x, vr.x, ar_[0]);
                ar_[1] = fdot2_(hv.y, vr.y, ar_[1]);
                ar_[2] = fdot2_(hv.z, vr.z, ar_[2]);
                ar_[3] = fdot2_(hv.w, vr.w, ar_[3]);
                ac_[0] = fdot2_(hv.x, vc.x, ac_[0]);
                ac_[1] = fdot2_(hv.y, vc.y, ac_[1]);
                ac_[2] = fdot2_(hv.z, vc.z, ac_[2]);
                ac_[3] = fdot2_(hv.w, vc.w, ac_[3]);
            }
            const float d0 = ((az[0]  + az[1])  + (az[2]  + az[3]))  + br0;
            const float d1 = ((ar_[0] + ar_[1]) + (ar_[2] + ar_[3])) + br1;
            const float d2 = ((ac_[0] + ac_[1]) + (ac_[2] + ac_[3])) + br2;

            const float z    = sigmoidf_(x0 + d0);
            const float r    = sigmoidf_(x1 + d1);
            const float hh   = tanh_fast(fmaf(r, d2, x2));
            const float hnew = fmaf(z, hprev - hh, hh);
            const float res  = (tok != 0) ? hnew : hprev;   // mask_zero carry
            hprev = res;

            s_h[u] = (f16)res;
            __builtin_amdgcn_wave_barrier();   // keep write before next reads

            const int tt = dir ? (S_ - 1 - t) : t;
            outb[(size_t)tt * (2 * H_)] = res; // coalesced 256B store, no wait
        }

        stage_write(buf ^ 1);   // vm wait happens here, once per 16 steps
        __builtin_amdgcn_wave_barrier();
    }
}

// x1 = sigmoid(gru_out @ w1 + b1), x2 = sigmoid(gru_out @ w2 + b2)
__global__ __launch_bounds__(256) void head_kernel(
    const float* __restrict__ gru,      // [B*S, 2H]
    const float* __restrict__ w1, const float* __restrict__ b1,
    const float* __restrict__ w2, const float* __restrict__ b2,
    float* __restrict__ x1, float* __restrict__ x2)
{
    __shared__ __align__(16) float s_w1[2 * H_];
    __shared__ __align__(16) float s_w2[2 * H_];
    const int tid = threadIdx.x;
    if (tid < 2 * H_)      s_w1[tid]          = w1[tid];
    else                   s_w2[tid - 2 * H_] = w2[tid - 2 * H_];
    __syncthreads();

    const int i = blockIdx.x * 256 + tid;
    const float4* g4 = (const float4*)(gru + (size_t)i * (2 * H_));
    float a1 = b1[0], a2 = b2[0];
    #pragma unroll
    for (int k = 0; k < (2 * H_) / 4; ++k) {
        const float4 v  = g4[k];
        const float4 q1 = ((const float4*)s_w1)[k];
        const float4 q2 = ((const float4*)s_w2)[k];
        a1 += v.x * q1.x + v.y * q1.y + v.z * q1.z + v.w * q1.w;
        a2 += v.x * q2.x + v.y * q2.y + v.z * q2.z + v.w * q2.w;
    }
    x1[i] = 1.0f / (1.0f + __expf(-a1));
    x2[i] = 1.0f / (1.0f + __expf(-a2));
}

extern "C" void kernel_launch(void* const* d_in, const int* in_sizes, int n_in,
                              void* d_out, int out_size, void* d_ws, size_t ws_size,
                              hipStream_t stream) {
    (void)in_sizes; (void)n_in; (void)ws_size; (void)out_size;

    const int*   inputs = (const int*)  d_in[0];
    const float* emb    = (const float*)d_in[1];
    const float* Wf     = (const float*)d_in[2];
    const float* Uf     = (const float*)d_in[3];
    const float* bif    = (const float*)d_in[4];
    const float* brf    = (const float*)d_in[5];
    const float* Wb     = (const float*)d_in[6];
    const float* Ub     = (const float*)d_in[7];
    const float* bib    = (const float*)d_in[8];
    const float* brb    = (const float*)d_in[9];
    const float* w1     = (const float*)d_in[10];
    const float* b1     = (const float*)d_in[11];
    const float* w2     = (const float*)d_in[12];
    const float* b2     = (const float*)d_in[13];

    float* out = (float*)d_out;
    float* x1  = out;                       // [B*S]
    float* x2  = out + (size_t)B_ * S_;     // [B*S]
    float* gru = out + (size_t)2 * B_ * S_; // [B*S, 2H]

    // workspace: proj [2][V][192] floats (7.67 MB), then Uh [2][192][32] u32 (48 KB)
    float* proj = (float*)d_ws;
    u32*   Uh   = (u32*)(proj + (size_t)2 * V_ * G3);

    proj_kernel<<<dim3((V_ + VCHUNK - 1) / VCHUNK, 2), 192, 0, stream>>>(
        emb, Wf, bif, Wb, bib, proj);
    upack_kernel<<<2, 256, 0, stream>>>(Uf, Ub, Uh);

    gru_scan9<<<B_ * 2, 64, 0, stream>>>(inputs, proj, Uh, brf, brb, gru);

    head_kernel<<<(B_ * S_) / 256, 256, 0, stream>>>(gru, w1, b1, w2, b2, x1, x2);
}